// Round 4
// 1445.889 us; speedup vs baseline: 1.0371x; 1.0371x over previous
//
#include <hip/hip_runtime.h>
#include <cmath>

#define T_STEPS 256
#define DIN  1024
#define DHID 1024
#define DOUT 1024
#define NB   128
#define BH   (DHID*NB)   // 131072 elems per h snapshot

typedef unsigned short u16;
typedef unsigned int   u32;
typedef unsigned long long u64;
typedef __attribute__((ext_vector_type(8))) __bf16 bf16x8;
typedef __attribute__((ext_vector_type(4))) float  f32x4;

__device__ __forceinline__ u16 f2bf(float f){
  u32 u = __builtin_bit_cast(u32, f);
  u32 r = (u + 0x7fffu + ((u >> 16) & 1u)) >> 16;   // RNE
  return (u16)r;
}
__device__ __forceinline__ float bf2f(u16 h){
  u32 u = ((u32)h) << 16;
  return __builtin_bit_cast(float, u);
}

// agent-scope (cross-XCD-coherent) accesses: bypass non-coherent L2,
// coherence point = shared L3. No cache-flush fences needed anywhere.
__device__ __forceinline__ u64 ld_agent_u64(const u64* p){
  return __hip_atomic_load(p, __ATOMIC_RELAXED, __HIP_MEMORY_SCOPE_AGENT);
}
__device__ __forceinline__ void st_agent_u64(u64* p, u64 v){
  __hip_atomic_store(p, v, __ATOMIC_RELAXED, __HIP_MEMORY_SCOPE_AGENT);
}

// ---------------- weight convert: 3x 1024x1024 fp32 -> bf16 ----------------
__global__ __launch_bounds__(256) void wconv(const float* __restrict__ w0,
                                             const float* __restrict__ w1,
                                             const float* __restrict__ w2,
                                             u16* __restrict__ dst){
  const int idx = blockIdx.x*256 + threadIdx.x;   // < 786432 (float4 units)
  const int seg = idx >> 18;                      // /262144
  const int off = idx & 262143;
  const float* src = seg==0 ? w0 : (seg==1 ? w1 : w2);
  const float4 v = ((const float4*)src)[off];
  ushort4 o = make_ushort4(f2bf(v.x), f2bf(v.y), f2bf(v.z), f2bf(v.w));
  ((ushort4*)dst)[idx] = o;
}

// ---------------- h_prev [HID][B] fp32 -> H_T[0] [B][HID] bf16 ----------------
__global__ __launch_bounds__(256) void hprevT(const float* __restrict__ hp,
                                              u16* __restrict__ HT0){
  const int tid = blockIdx.x*256 + threadIdx.x;   // < 131072
  const int b = tid >> 10, m = tid & 1023;
  HT0[tid] = f2bf(hp[(size_t)m*NB + b]);
}

// ---------------- X [T][IN][B] fp32 -> X^T [T][B][IN] bf16 ----------------
__global__ __launch_bounds__(256) void xT_k(const float* __restrict__ x,
                                            u16* __restrict__ xt){
  __shared__ float tile[64][65];
  const int t  = blockIdx.z;
  const int k0 = blockIdx.y*64;
  const int b0 = blockIdx.x*64;
  const int tx = threadIdx.x & 63, ty = threadIdx.x >> 6;  // ty 0..3
  const float* src = x + (size_t)t*DIN*NB + (size_t)k0*NB + b0;
#pragma unroll
  for(int r=0;r<16;r++){ int k = r*4 + ty; tile[k][tx] = src[(size_t)k*NB + tx]; }
  __syncthreads();
  u16* dst = xt + (size_t)t*NB*DIN + (size_t)b0*DIN + k0;
#pragma unroll
  for(int r=0;r<16;r++){ int b = r*4 + ty; dst[(size_t)b*DIN + tx] = f2bf(tile[tx][b]); }
}

// ---------------- A[t] = X^T[t] @ Wxh^T + bh  -> bf16 [T][B][HID] ----------------
__global__ __launch_bounds__(256) void gemm_xw(const u16* __restrict__ XT,
                                               const u16* __restrict__ WxB,
                                               const float* __restrict__ bh,
                                               u16* __restrict__ AT){
  const int t  = blockIdx.y;
  const int mj = blockIdx.x;
  __shared__ __align__(16) u16 As[128*40];
  __shared__ __align__(16) u16 Bs[128*40];
  const u16* aG = XT + (size_t)t*NB*DIN;          // rows = b (128), K-contig
  const u16* bG = WxB + (size_t)mj*128*DIN;       // rows = m slice, K-contig
  const int tid = threadIdx.x;
  const int lane = tid & 63, w = tid >> 6;
  const int wr = (w & 1)*64, wc = (w >> 1)*64;
  const int l15 = lane & 15, q = lane >> 4;
  const int sr = tid >> 2;            // 0..63
  const int sk = (tid & 3)*8;         // 0,8,16,24

  f32x4 acc[4][4] = {};
  uint4 pa0 = *(const uint4*)&aG[(size_t)sr*DIN + sk];
  uint4 pa1 = *(const uint4*)&aG[(size_t)(sr+64)*DIN + sk];
  uint4 pb0 = *(const uint4*)&bG[(size_t)sr*DIN + sk];
  uint4 pb1 = *(const uint4*)&bG[(size_t)(sr+64)*DIN + sk];

  for(int it = 0; it < DIN/32; ++it){
    __syncthreads();
    *(uint4*)&As[sr*40 + sk]      = pa0;
    *(uint4*)&As[(sr+64)*40 + sk] = pa1;
    *(uint4*)&Bs[sr*40 + sk]      = pb0;
    *(uint4*)&Bs[(sr+64)*40 + sk] = pb1;
    __syncthreads();
    if(it < DIN/32 - 1){
      const int k0 = (it+1)*32;
      pa0 = *(const uint4*)&aG[(size_t)sr*DIN + k0 + sk];
      pa1 = *(const uint4*)&aG[(size_t)(sr+64)*DIN + k0 + sk];
      pb0 = *(const uint4*)&bG[(size_t)sr*DIN + k0 + sk];
      pb1 = *(const uint4*)&bG[(size_t)(sr+64)*DIN + k0 + sk];
    }
    bf16x8 af[4], bf[4];
#pragma unroll
    for(int i=0;i<4;i++) af[i] = *(const bf16x8*)&As[(wr + i*16 + l15)*40 + q*8];
#pragma unroll
    for(int j=0;j<4;j++) bf[j] = *(const bf16x8*)&Bs[(wc + j*16 + l15)*40 + q*8];
#pragma unroll
    for(int i=0;i<4;i++)
#pragma unroll
      for(int j=0;j<4;j++)
        acc[i][j] = __builtin_amdgcn_mfma_f32_16x16x32_bf16(af[i], bf[j], acc[i][j], 0,0,0);
  }

  u16* out = AT + (size_t)t*NB*DHID;
#pragma unroll
  for(int j=0;j<4;j++){
    const int mg = mj*128 + wc + j*16 + l15;
    const float bhv = bh[mg];
#pragma unroll
    for(int i=0;i<4;i++){
#pragma unroll
      for(int r=0;r<4;r++){
        const int bg = wr + i*16 + q*4 + r;     // D row = A-operand m-index (=b here)
        out[(size_t)bg*DHID + mg] = f2bf(acc[i][j][r] + bhv);
      }
    }
  }
}

// ---------------- persistent recurrence: all 256 steps in one launch ----------------
// grid = 64 blocks (8 m-slices x 8 b-groups) x 256 thr (4 waves, m=32 per wave).
// Whh fragments pinned in VGPR/AGPR for the entire kernel (64 x bf16x8 per lane).
// Sync: per-(bg,ms) flags on separate 128B lines. Block (ms,bg) consumes only
// H rows of its bg -> waits only for the 8 producers of that bg (not all 64).
// H exchanged via agent-scope accesses -> coherent at shared L3.
#define RSTEP_BLOCKS 64
__global__ __launch_bounds__(256, 1) void rnn_steps(const u16* __restrict__ WhB,
                                                    const u16* __restrict__ AT,
                                                    u16* __restrict__ HT,
                                                    u32* __restrict__ flags){
  const int mslice = blockIdx.x & 7;    // m_tile = 128 (32 per wave)
  const int bg     = blockIdx.x >> 3;   // b_tile = 16
  __shared__ __align__(16) u16 Hs[16*1032];   // 16 rows x 1024, pad +8
  __shared__ __align__(16) u16 Es[4*16*40];   // per-wave epilogue transpose buf
  const int tid = threadIdx.x;
  const int lane = tid & 63, w = tid >> 6;    // w 0..3
  const int l15 = lane & 15, q = lane >> 4, q8 = q*8;
  const int mw = mslice*128 + w*32;           // wave's m sub-slice base (32 wide)

  // ---- load Whh B-fragments into registers, once (2 m-halves x 32 kk) ----
  bf16x8 wf0[32], wf1[32];
  { const u16* ws0 = WhB + (size_t)(mw + l15)*DHID;
    const u16* ws1 = WhB + (size_t)(mw + 16 + l15)*DHID;
#pragma unroll
    for(int i=0;i<32;i++){ wf0[i] = *(const bf16x8*)&ws0[i*32 + q8];
                           wf1[i] = *(const bf16x8*)&ws1[i*32 + q8]; }
  }

  // staging: 256 thr, 16 rows; a row is 1024 u16 = 256 u64.
  // thread -> row tid>>4, u64 cols (tid&15) + i*16, i=0..15  (full 0..255 coverage)
  const int hr = tid >> 4;         // 0..15
  const int hc = tid & 15;         // u64 col base
  // epilogue transpose read coords
  const int eb = lane >> 2, ec = lane & 3;

  for(int t=0; t<T_STEPS; ++t){
    const u64* Hp64 = (const u64*)(HT + (size_t)t*BH + (size_t)(bg*16 + hr)*DHID) + hc;

    // issue coherent H loads first (longest latency)
    u64 hv[16];
#pragma unroll
    for(int i=0;i<16;i++) hv[i] = ld_agent_u64(Hp64 + i*16);

    // epilogue addend (read-only, plain cached loads)
    const u16* At = AT + (size_t)t*BH;
    u16 aval[2][4];
#pragma unroll
    for(int h=0;h<2;h++)
#pragma unroll
      for(int r=0;r<4;r++)
        aval[h][r] = At[(size_t)(bg*16 + q*4 + r)*DHID + mw + h*16 + l15];

    u64* hs64 = (u64*)&Hs[hr*1032] + hc;
#pragma unroll
    for(int i=0;i<16;i++) hs64[i*16] = hv[i];
    __syncthreads();

    // one A-fragment read feeds TWO MFMAs (m-halves) -> halved LDS traffic.
    // even/odd-kk partial accumulators -> 4 independent MFMA dep-chains
    // (1 wave/SIMD: no TLP to hide dependent-MFMA latency, need ILP)
    f32x4 a0e = {0,0,0,0}, a0o = {0,0,0,0}, a1e = {0,0,0,0}, a1o = {0,0,0,0};
#pragma unroll
    for(int kk=0;kk<32;kk+=2){
      bf16x8 ae = *(const bf16x8*)&Hs[l15*1032 + kk*32 + q8];
      bf16x8 ao = *(const bf16x8*)&Hs[l15*1032 + (kk+1)*32 + q8];
      a0e = __builtin_amdgcn_mfma_f32_16x16x32_bf16(ae, wf0[kk],   a0e, 0,0,0);
      a1e = __builtin_amdgcn_mfma_f32_16x16x32_bf16(ae, wf1[kk],   a1e, 0,0,0);
      a0o = __builtin_amdgcn_mfma_f32_16x16x32_bf16(ao, wf0[kk+1], a0o, 0,0,0);
      a1o = __builtin_amdgcn_mfma_f32_16x16x32_bf16(ao, wf1[kk+1], a1o, 0,0,0);
    }
    f32x4 acc0 = a0e + a0o, acc1 = a1e + a1o;

    // epilogue: tanh -> LDS transpose -> two coalesced 8B agent stores/thread
    u16* Ew = Es + w*640;
#pragma unroll
    for(int r=0;r<4;r++){
      float v0 = acc0[r] + bf2f(aval[0][r]);
      float v1 = acc1[r] + bf2f(aval[1][r]);
      Ew[(q*4+r)*40 + l15]      = f2bf(tanhf(v0));
      Ew[(q*4+r)*40 + 16 + l15] = f2bf(tanhf(v1));
    }
    // ORDERING FIX: Ew is written as u16, read back as u64 -> TBAA says "no
    // alias" and the compiler may hoist the read above the writes (round-3
    // failure: stale h, absmax 0.56). Barrier forces compiler ordering +
    // lgkmcnt drain. (~100cy/step, negligible.)
    __syncthreads();
    u64 h0 = *(const u64*)&Ew[eb*40 + ec*8];
    u64 h1 = *(const u64*)&Ew[eb*40 + ec*8 + 4];
    u64* Hn = (u64*)(HT + (size_t)(t+1)*BH + (size_t)(bg*16 + eb)*DHID + mw + ec*8);
    st_agent_u64(Hn,     h0);
    st_agent_u64(Hn + 1, h1);

    // drain own stores to the coherence point before raising the flag
    asm volatile("s_waitcnt vmcnt(0)" ::: "memory");

    if(t < T_STEPS-1){
      __syncthreads();   // all threads' stores drained before flag goes up
      if(tid == 0)
        __hip_atomic_store(&flags[(size_t)(bg*8 + mslice)*32], (u32)(t+1),
                           __ATOMIC_RELAXED, __HIP_MEMORY_SCOPE_AGENT);
      // wait for the 8 producers of this bg (divergent-exit poll = max-wait)
      if(tid < 8){
        while(__hip_atomic_load(&flags[(size_t)(bg*8 + tid)*32],
                                __ATOMIC_RELAXED, __HIP_MEMORY_SCOPE_AGENT) < (u32)(t+1))
          ;
      }
      __syncthreads();   // also protects Hs reuse next iteration
    }
  }
}

// ---------------- Y[t] = Why @ h_t + by  -> fp32 [T][OUT][B] ----------------
__global__ __launch_bounds__(256) void gemm_hy(const u16* __restrict__ WyB,
                                               const u16* __restrict__ HT,
                                               const float* __restrict__ by,
                                               float* __restrict__ Y){
  const int t  = blockIdx.y;
  const int mi = blockIdx.x;
  __shared__ __align__(16) u16 As[128*40];
  __shared__ __align__(16) u16 Bs[128*40];
  const u16* aG = WyB + (size_t)mi*128*DHID;       // rows = out slice
  const u16* bG = HT  + (size_t)(t+1)*BH;          // rows = b (128)
  const int tid = threadIdx.x;
  const int lane = tid & 63, w = tid >> 6;
  const int wr = (w & 1)*64, wc = (w >> 1)*64;
  const int l15 = lane & 15, q = lane >> 4;
  const int sr = tid >> 2;
  const int sk = (tid & 3)*8;

  f32x4 acc[4][4] = {};
  uint4 pa0 = *(const uint4*)&aG[(size_t)sr*DHID + sk];
  uint4 pa1 = *(const uint4*)&aG[(size_t)(sr+64)*DHID + sk];
  uint4 pb0 = *(const uint4*)&bG[(size_t)sr*DHID + sk];
  uint4 pb1 = *(const uint4*)&bG[(size_t)(sr+64)*DHID + sk];

  for(int it = 0; it < DHID/32; ++it){
    __syncthreads();
    *(uint4*)&As[sr*40 + sk]      = pa0;
    *(uint4*)&As[(sr+64)*40 + sk] = pa1;
    *(uint4*)&Bs[sr*40 + sk]      = pb0;
    *(uint4*)&Bs[(sr+64)*40 + sk] = pb1;
    __syncthreads();
    if(it < DHID/32 - 1){
      const int k0 = (it+1)*32;
      pa0 = *(const uint4*)&aG[(size_t)sr*DHID + k0 + sk];
      pa1 = *(const uint4*)&aG[(size_t)(sr+64)*DHID + k0 + sk];
      pb0 = *(const uint4*)&bG[(size_t)sr*DHID + k0 + sk];
      pb1 = *(const uint4*)&bG[(size_t)(sr+64)*DHID + k0 + sk];
    }
    bf16x8 af[4], bf[4];
#pragma unroll
    for(int i=0;i<4;i++) af[i] = *(const bf16x8*)&As[(wr + i*16 + l15)*40 + q*8];
#pragma unroll
    for(int j=0;j<4;j++) bf[j] = *(const bf16x8*)&Bs[(wc + j*16 + l15)*40 + q*8];
#pragma unroll
    for(int i=0;i<4;i++)
#pragma unroll
      for(int j=0;j<4;j++)
        acc[i][j] = __builtin_amdgcn_mfma_f32_16x16x32_bf16(af[i], bf[j], acc[i][j], 0,0,0);
  }

  float* out = Y + (size_t)t*DOUT*NB;
#pragma unroll
  for(int i=0;i<4;i++){
#pragma unroll
    for(int r=0;r<4;r++){
      const int og = mi*128 + wr + i*16 + q*4 + r;  // D row = out index
      const float byv = by[og];
#pragma unroll
      for(int j=0;j<4;j++){
        const int bg = wc + j*16 + l15;             // D col = batch index
        out[(size_t)og*NB + bg] = acc[i][j][r] + byv;
      }
    }
  }
}

// ---------------- h_final: H_T[T] [B][HID] bf16 -> [HID][B] fp32 ----------------
__global__ __launch_bounds__(256) void hfinal(const u16* __restrict__ HT,
                                              float* __restrict__ dst){
  const int tid = blockIdx.x*256 + threadIdx.x;   // < 131072
  const int m = tid >> 7, b = tid & 127;
  dst[tid] = bf2f(HT[(size_t)T_STEPS*BH + (size_t)b*DHID + m]);
}

extern "C" void kernel_launch(void* const* d_in, const int* in_sizes, int n_in,
                              void* d_out, int out_size, void* d_ws, size_t ws_size,
                              hipStream_t stream)
{
  const float* x   = (const float*)d_in[0];   // [T, IN, B]
  const float* hp  = (const float*)d_in[1];   // [HID, B]
  const float* wxh = (const float*)d_in[2];   // [HID, IN]
  const float* whh = (const float*)d_in[3];   // [HID, HID]
  const float* why = (const float*)d_in[4];   // [OUT, HID]
  const float* bh  = (const float*)d_in[5];   // [HID, 1]
  const float* by  = (const float*)d_in[6];   // [OUT, 1]
  float* out = (float*)d_out;

  // workspace: bf16 weights (6 MB) + H_T (T+1 snapshots, 64.25 MB) + flags
  u16* WxB = (u16*)d_ws;
  u16* WhB = WxB + (size_t)1024*1024;
  u16* WyB = WhB + (size_t)1024*1024;
  u16* HT  = WyB + (size_t)1024*1024;
  u32* flags = (u32*)(HT + (size_t)(T_STEPS+1)*BH);   // 8 bg x 8 ms x 128B

  // temporaries inside d_out (dead before gemm_hy overwrites):
  u16* XT = (u16*)d_out;
  u16* AT = XT + (size_t)T_STEPS*NB*DIN;

  wconv  <<<3072, 256, 0, stream>>>(wxh, whh, why, WxB);
  hprevT <<<512,  256, 0, stream>>>(hp, HT);
  xT_k   <<<dim3(2,16,T_STEPS), 256, 0, stream>>>(x, XT);
  gemm_xw<<<dim3(8,T_STEPS),    256, 0, stream>>>(XT, WxB, bh, AT);
  (void)hipMemsetAsync(flags, 0, 8192, stream);
  rnn_steps<<<RSTEP_BLOCKS, 256, 0, stream>>>(WhB, AT, HT, flags);
  gemm_hy<<<dim3(8,T_STEPS), 256, 0, stream>>>(WyB, HT, by, out);
  hfinal <<<512, 256, 0, stream>>>(HT, out + (size_t)T_STEPS*DOUT*NB);
}

// Round 5
// 1425.902 us; speedup vs baseline: 1.0517x; 1.0140x over previous
//
#include <hip/hip_runtime.h>
#include <cmath>

#define T_STEPS 256
#define DIN  1024
#define DHID 1024
#define DOUT 1024
#define NB   128
#define BH   (DHID*NB)   // 131072 elems per h snapshot

typedef unsigned short u16;
typedef unsigned int   u32;
typedef unsigned long long u64;
typedef __attribute__((ext_vector_type(8))) __bf16 bf16x8;
typedef __attribute__((ext_vector_type(4))) float  f32x4;

__device__ __forceinline__ u16 f2bf(float f){
  u32 u = __builtin_bit_cast(u32, f);
  u32 r = (u + 0x7fffu + ((u >> 16) & 1u)) >> 16;   // RNE
  return (u16)r;
}
__device__ __forceinline__ float bf2f(u16 h){
  u32 u = ((u32)h) << 16;
  return __builtin_bit_cast(float, u);
}

// agent-scope (cross-XCD-coherent) accesses: bypass non-coherent L2,
// coherence point = shared L3.
__device__ __forceinline__ u32 ld_agent_u32(const u32* p){
  return __hip_atomic_load(p, __ATOMIC_RELAXED, __HIP_MEMORY_SCOPE_AGENT);
}
__device__ __forceinline__ void st_agent_u64(u64* p, u64 v){
  __hip_atomic_store(p, v, __ATOMIC_RELAXED, __HIP_MEMORY_SCOPE_AGENT);
}
// async global->LDS, 16B per lane, wave-uniform LDS base + lane*16 (HW rule)
__device__ __forceinline__ void gload_lds16(const void* g, void* l){
  __builtin_amdgcn_global_load_lds(
      (const __attribute__((address_space(1))) unsigned int*)g,
      (__attribute__((address_space(3))) unsigned int*)l, 16, 0, 0);
}

// ---------------- weight convert: 3x 1024x1024 fp32 -> bf16 ----------------
__global__ __launch_bounds__(256) void wconv(const float* __restrict__ w0,
                                             const float* __restrict__ w1,
                                             const float* __restrict__ w2,
                                             u16* __restrict__ dst){
  const int idx = blockIdx.x*256 + threadIdx.x;   // < 786432 (float4 units)
  const int seg = idx >> 18;                      // /262144
  const int off = idx & 262143;
  const float* src = seg==0 ? w0 : (seg==1 ? w1 : w2);
  const float4 v = ((const float4*)src)[off];
  ushort4 o = make_ushort4(f2bf(v.x), f2bf(v.y), f2bf(v.z), f2bf(v.w));
  ((ushort4*)dst)[idx] = o;
}

// ---------------- h_prev [HID][B] fp32 -> H_T[0] [B][HID] bf16 ----------------
__global__ __launch_bounds__(256) void hprevT(const float* __restrict__ hp,
                                              u16* __restrict__ HT0){
  const int tid = blockIdx.x*256 + threadIdx.x;   // < 131072
  const int b = tid >> 10, m = tid & 1023;
  HT0[tid] = f2bf(hp[(size_t)m*NB + b]);
}

// ---------------- X [T][IN][B] fp32 -> X^T [T][B][IN] bf16 ----------------
__global__ __launch_bounds__(256) void xT_k(const float* __restrict__ x,
                                            u16* __restrict__ xt){
  __shared__ float tile[64][65];
  const int t  = blockIdx.z;
  const int k0 = blockIdx.y*64;
  const int b0 = blockIdx.x*64;
  const int tx = threadIdx.x & 63, ty = threadIdx.x >> 6;  // ty 0..3
  const float* src = x + (size_t)t*DIN*NB + (size_t)k0*NB + b0;
#pragma unroll
  for(int r=0;r<16;r++){ int k = r*4 + ty; tile[k][tx] = src[(size_t)k*NB + tx]; }
  __syncthreads();
  u16* dst = xt + (size_t)t*NB*DIN + (size_t)b0*DIN + k0;
#pragma unroll
  for(int r=0;r<16;r++){ int b = r*4 + ty; dst[(size_t)b*DIN + tx] = f2bf(tile[tx][b]); }
}

// ---------------- A[t] = X^T[t] @ Wxh^T + bh  -> bf16 [T][B][HID] ----------------
__global__ __launch_bounds__(256) void gemm_xw(const u16* __restrict__ XT,
                                               const u16* __restrict__ WxB,
                                               const float* __restrict__ bh,
                                               u16* __restrict__ AT){
  const int t  = blockIdx.y;
  const int mj = blockIdx.x;
  __shared__ __align__(16) u16 As[128*40];
  __shared__ __align__(16) u16 Bs[128*40];
  const u16* aG = XT + (size_t)t*NB*DIN;          // rows = b (128), K-contig
  const u16* bG = WxB + (size_t)mj*128*DIN;       // rows = m slice, K-contig
  const int tid = threadIdx.x;
  const int lane = tid & 63, w = tid >> 6;
  const int wr = (w & 1)*64, wc = (w >> 1)*64;
  const int l15 = lane & 15, q = lane >> 4;
  const int sr = tid >> 2;            // 0..63
  const int sk = (tid & 3)*8;         // 0,8,16,24

  f32x4 acc[4][4] = {};
  uint4 pa0 = *(const uint4*)&aG[(size_t)sr*DIN + sk];
  uint4 pa1 = *(const uint4*)&aG[(size_t)(sr+64)*DIN + sk];
  uint4 pb0 = *(const uint4*)&bG[(size_t)sr*DIN + sk];
  uint4 pb1 = *(const uint4*)&bG[(size_t)(sr+64)*DIN + sk];

  for(int it = 0; it < DIN/32; ++it){
    __syncthreads();
    *(uint4*)&As[sr*40 + sk]      = pa0;
    *(uint4*)&As[(sr+64)*40 + sk] = pa1;
    *(uint4*)&Bs[sr*40 + sk]      = pb0;
    *(uint4*)&Bs[(sr+64)*40 + sk] = pb1;
    __syncthreads();
    if(it < DIN/32 - 1){
      const int k0 = (it+1)*32;
      pa0 = *(const uint4*)&aG[(size_t)sr*DIN + k0 + sk];
      pa1 = *(const uint4*)&aG[(size_t)(sr+64)*DIN + k0 + sk];
      pb0 = *(const uint4*)&bG[(size_t)sr*DIN + k0 + sk];
      pb1 = *(const uint4*)&bG[(size_t)(sr+64)*DIN + k0 + sk];
    }
    bf16x8 af[4], bf[4];
#pragma unroll
    for(int i=0;i<4;i++) af[i] = *(const bf16x8*)&As[(wr + i*16 + l15)*40 + q*8];
#pragma unroll
    for(int j=0;j<4;j++) bf[j] = *(const bf16x8*)&Bs[(wc + j*16 + l15)*40 + q*8];
#pragma unroll
    for(int i=0;i<4;i++)
#pragma unroll
      for(int j=0;j<4;j++)
        acc[i][j] = __builtin_amdgcn_mfma_f32_16x16x32_bf16(af[i], bf[j], acc[i][j], 0,0,0);
  }

  u16* out = AT + (size_t)t*NB*DHID;
#pragma unroll
  for(int j=0;j<4;j++){
    const int mg = mj*128 + wc + j*16 + l15;
    const float bhv = bh[mg];
#pragma unroll
    for(int i=0;i<4;i++){
#pragma unroll
      for(int r=0;r<4;r++){
        const int bg = wr + i*16 + q*4 + r;     // D row = A-operand m-index (=b here)
        out[(size_t)bg*DHID + mg] = f2bf(acc[i][j][r] + bhv);
      }
    }
  }
}

// ---------------- persistent recurrence: all 256 steps in one launch ----------------
// grid = 64 blocks (8 m-slices x 8 b-groups) x 256 thr (4 waves, m=32 per wave).
// Latency-chain-optimized step:
//   poll(all lanes, divergent) -> global_load_lds H -> barrier -> MFMA ->
//   epilogue (Es wave-private transpose, threadfence_block only) ->
//   agent stores -> vmcnt(0) -> barrier -> flag -> aval(t+1) prefetch.
// 2 barriers/step (was 4). aval HBM latency hidden under poll+stage of next step.
// Coherence: producers store h via sc0sc1 (L3, no L2 alloc); consumers may use
// PLAIN cached loads because every HT[t] line is first-touch on the reading CU
// (snapshots are distinct addresses, only ever written via sc stores).
// Flags stay agent-scope (re-polled, must bypass caches).
#define RSTEP_BLOCKS 64
__global__ __launch_bounds__(256, 1) void rnn_steps(const u16* __restrict__ WhB,
                                                    const u16* __restrict__ AT,
                                                    u16* __restrict__ HT,
                                                    u32* __restrict__ flags){
  const int mslice = blockIdx.x & 7;    // m_tile = 128 (32 per wave)
  const int bg     = blockIdx.x >> 3;   // b_tile = 16
  __shared__ __align__(16) u16 Hs[16*1032];   // 16 rows x 1024, pad +8
  __shared__ __align__(16) u16 Es[4*16*40];   // per-wave epilogue transpose buf
  const int tid = threadIdx.x;
  const int lane = tid & 63, w = tid >> 6;    // w 0..3
  const int l15 = lane & 15, q = lane >> 4, q8 = q*8;
  const int mw = mslice*128 + w*32;           // wave's m sub-slice base (32 wide)

  // ---- load Whh B-fragments into registers, once (2 m-halves x 32 kk) ----
  bf16x8 wf0[32], wf1[32];
  { const u16* ws0 = WhB + (size_t)(mw + l15)*DHID;
    const u16* ws1 = WhB + (size_t)(mw + 16 + l15)*DHID;
#pragma unroll
    for(int i=0;i<32;i++){ wf0[i] = *(const bf16x8*)&ws0[i*32 + q8];
                           wf1[i] = *(const bf16x8*)&ws1[i*32 + q8]; }
  }

  // epilogue transpose read coords
  const int eb = lane >> 2, ec = lane & 3;
  // all-lane poll address: lane l watches producer (l&7) of this bg
  const u32* fl = &flags[(size_t)(bg*8 + (lane & 7))*32];

  // aval(t) prefetch registers (loaded one step ahead; t=0 in prologue)
  u16 avn[2][4];
#pragma unroll
  for(int h=0;h<2;h++)
#pragma unroll
    for(int r=0;r<4;r++)
      avn[h][r] = AT[(size_t)(bg*16 + q*4 + r)*DHID + mw + h*16 + l15];

  for(int t=0; t<T_STEPS; ++t){
    // ---- 1. wait for the 8 producers of this bg (divergent-exit = all-ready) ----
    // t=0: flags are 0 >= 0, no wait (HT[0] pre-flushed by hprevT kernel boundary).
    while(ld_agent_u32(fl) < (u32)t)
      ;

    // ---- 2. stage H(t)[bg rows] straight into LDS (no VGPR round trip) ----
    { const u16* hbase = HT + (size_t)t*BH + (size_t)(bg*16)*DHID;
#pragma unroll
      for(int i=0;i<4;i++){
        const int row = w*4 + i;                     // wave-uniform
#pragma unroll
        for(int half=0; half<2; half++){
          const u16* gp = hbase + (size_t)row*DHID + half*512 + lane*8;  // 16B/lane
          gload_lds16(gp, &Hs[row*1032 + half*512]); // lds base wave-uniform
        }
      }
    }
    __syncthreads();   // Hs ready (implicit vmcnt(0) also retires aval prefetch)

    // ---- 3. MFMA: one A-read feeds two m-halves; even/odd kk dep-chains ----
    f32x4 a0e = {0,0,0,0}, a0o = {0,0,0,0}, a1e = {0,0,0,0}, a1o = {0,0,0,0};
#pragma unroll
    for(int kk=0;kk<32;kk+=2){
      bf16x8 ae = *(const bf16x8*)&Hs[l15*1032 + kk*32 + q8];
      bf16x8 ao = *(const bf16x8*)&Hs[l15*1032 + (kk+1)*32 + q8];
      a0e = __builtin_amdgcn_mfma_f32_16x16x32_bf16(ae, wf0[kk],   a0e, 0,0,0);
      a1e = __builtin_amdgcn_mfma_f32_16x16x32_bf16(ae, wf1[kk],   a1e, 0,0,0);
      a0o = __builtin_amdgcn_mfma_f32_16x16x32_bf16(ao, wf0[kk+1], a0o, 0,0,0);
      a1o = __builtin_amdgcn_mfma_f32_16x16x32_bf16(ao, wf1[kk+1], a1o, 0,0,0);
    }
    f32x4 acc0 = a0e + a0o, acc1 = a1e + a1o;

    // ---- 4. epilogue: tanh -> wave-private LDS transpose -> 2x 8B agent stores ----
    u16* Ew = Es + w*640;
#pragma unroll
    for(int r=0;r<4;r++){
      float v0 = acc0[r] + bf2f(avn[0][r]);
      float v1 = acc1[r] + bf2f(avn[1][r]);
      Ew[(q*4+r)*40 + l15]      = f2bf(tanhf(v0));
      Ew[(q*4+r)*40 + 16 + l15] = f2bf(tanhf(v1));
    }
    // Es is WAVE-PRIVATE: wave-lockstep ordering suffices; the fence is a
    // type-blind compiler+lgkm barrier that stops the TBAA hoist (round-3 bug)
    // without a full workgroup barrier.
    __threadfence_block();
    u64 h0 = *(const u64*)&Ew[eb*40 + ec*8];
    u64 h1 = *(const u64*)&Ew[eb*40 + ec*8 + 4];
    u64* Hn = (u64*)(HT + (size_t)(t+1)*BH + (size_t)(bg*16 + eb)*DHID + mw + ec*8);
    st_agent_u64(Hn,     h0);
    st_agent_u64(Hn + 1, h1);

    // ---- 5. drain own stores to L3, block-wide rendezvous, raise flag ----
    asm volatile("s_waitcnt vmcnt(0)" ::: "memory");
    __syncthreads();   // all waves drained + done reading Hs (safe to overwrite next iter)

    if(t < T_STEPS-1){
      if(tid == 0)
        __hip_atomic_store(&flags[(size_t)(bg*8 + mslice)*32], (u32)(t+1),
                           __ATOMIC_RELAXED, __HIP_MEMORY_SCOPE_AGENT);
      // ---- 6. prefetch aval(t+1) NOW: HBM latency hides under poll+stage ----
      const u16* At = AT + (size_t)(t+1)*BH;
#pragma unroll
      for(int h=0;h<2;h++)
#pragma unroll
        for(int r=0;r<4;r++)
          avn[h][r] = At[(size_t)(bg*16 + q*4 + r)*DHID + mw + h*16 + l15];
    }
  }
}

// ---------------- Y[t] = Why @ h_t + by  -> fp32 [T][OUT][B] ----------------
__global__ __launch_bounds__(256) void gemm_hy(const u16* __restrict__ WyB,
                                               const u16* __restrict__ HT,
                                               const float* __restrict__ by,
                                               float* __restrict__ Y){
  const int t  = blockIdx.y;
  const int mi = blockIdx.x;
  __shared__ __align__(16) u16 As[128*40];
  __shared__ __align__(16) u16 Bs[128*40];
  const u16* aG = WyB + (size_t)mi*128*DHID;       // rows = out slice
  const u16* bG = HT  + (size_t)(t+1)*BH;          // rows = b (128)
  const int tid = threadIdx.x;
  const int lane = tid & 63, w = tid >> 6;
  const int wr = (w & 1)*64, wc = (w >> 1)*64;
  const int l15 = lane & 15, q = lane >> 4;
  const int sr = tid >> 2;
  const int sk = (tid & 3)*8;

  f32x4 acc[4][4] = {};
  uint4 pa0 = *(const uint4*)&aG[(size_t)sr*DHID + sk];
  uint4 pa1 = *(const uint4*)&aG[(size_t)(sr+64)*DHID + sk];
  uint4 pb0 = *(const uint4*)&bG[(size_t)sr*DHID + sk];
  uint4 pb1 = *(const uint4*)&bG[(size_t)(sr+64)*DHID + sk];

  for(int it = 0; it < DHID/32; ++it){
    __syncthreads();
    *(uint4*)&As[sr*40 + sk]      = pa0;
    *(uint4*)&As[(sr+64)*40 + sk] = pa1;
    *(uint4*)&Bs[sr*40 + sk]      = pb0;
    *(uint4*)&Bs[(sr+64)*40 + sk] = pb1;
    __syncthreads();
    if(it < DHID/32 - 1){
      const int k0 = (it+1)*32;
      pa0 = *(const uint4*)&aG[(size_t)sr*DHID + k0 + sk];
      pa1 = *(const uint4*)&aG[(size_t)(sr+64)*DHID + k0 + sk];
      pb0 = *(const uint4*)&bG[(size_t)sr*DHID + k0 + sk];
      pb1 = *(const uint4*)&bG[(size_t)(sr+64)*DHID + k0 + sk];
    }
    bf16x8 af[4], bf[4];
#pragma unroll
    for(int i=0;i<4;i++) af[i] = *(const bf16x8*)&As[(wr + i*16 + l15)*40 + q*8];
#pragma unroll
    for(int j=0;j<4;j++) bf[j] = *(const bf16x8*)&Bs[(wc + j*16 + l15)*40 + q*8];
#pragma unroll
    for(int i=0;i<4;i++)
#pragma unroll
      for(int j=0;j<4;j++)
        acc[i][j] = __builtin_amdgcn_mfma_f32_16x16x32_bf16(af[i], bf[j], acc[i][j], 0,0,0);
  }

  float* out = Y + (size_t)t*DOUT*NB;
#pragma unroll
  for(int i=0;i<4;i++){
#pragma unroll
    for(int r=0;r<4;r++){
      const int og = mi*128 + wr + i*16 + q*4 + r;  // D row = out index
      const float byv = by[og];
#pragma unroll
      for(int j=0;j<4;j++){
        const int bg = wc + j*16 + l15;             // D col = batch index
        out[(size_t)og*NB + bg] = acc[i][j][r] + byv;
      }
    }
  }
}

// ---------------- h_final: H_T[T] [B][HID] bf16 -> [HID][B] fp32 ----------------
__global__ __launch_bounds__(256) void hfinal(const u16* __restrict__ HT,
                                              float* __restrict__ dst){
  const int tid = blockIdx.x*256 + threadIdx.x;   // < 131072
  const int m = tid >> 7, b = tid & 127;
  dst[tid] = bf2f(HT[(size_t)T_STEPS*BH + (size_t)b*DHID + m]);
}

extern "C" void kernel_launch(void* const* d_in, const int* in_sizes, int n_in,
                              void* d_out, int out_size, void* d_ws, size_t ws_size,
                              hipStream_t stream)
{
  const float* x   = (const float*)d_in[0];   // [T, IN, B]
  const float* hp  = (const float*)d_in[1];   // [HID, B]
  const float* wxh = (const float*)d_in[2];   // [HID, IN]
  const float* whh = (const float*)d_in[3];   // [HID, HID]
  const float* why = (const float*)d_in[4];   // [OUT, HID]
  const float* bh  = (const float*)d_in[5];   // [HID, 1]
  const float* by  = (const float*)d_in[6];   // [OUT, 1]
  float* out = (float*)d_out;

  // workspace: bf16 weights (6 MB) + H_T (T+1 snapshots, 64.25 MB) + flags
  u16* WxB = (u16*)d_ws;
  u16* WhB = WxB + (size_t)1024*1024;
  u16* WyB = WhB + (size_t)1024*1024;
  u16* HT  = WyB + (size_t)1024*1024;
  u32* flags = (u32*)(HT + (size_t)(T_STEPS+1)*BH);   // 8 bg x 8 ms x 128B

  // temporaries inside d_out (dead before gemm_hy overwrites):
  u16* XT = (u16*)d_out;
  u16* AT = XT + (size_t)T_STEPS*NB*DIN;

  wconv  <<<3072, 256, 0, stream>>>(wxh, whh, why, WxB);
  hprevT <<<512,  256, 0, stream>>>(hp, HT);
  xT_k   <<<dim3(2,16,T_STEPS), 256, 0, stream>>>(x, XT);
  gemm_xw<<<dim3(8,T_STEPS),    256, 0, stream>>>(XT, WxB, bh, AT);
  (void)hipMemsetAsync(flags, 0, 8192, stream);
  rnn_steps<<<RSTEP_BLOCKS, 256, 0, stream>>>(WhB, AT, HT, flags);
  gemm_hy<<<dim3(8,T_STEPS), 256, 0, stream>>>(WyB, HT, by, out);
  hfinal <<<512, 256, 0, stream>>>(HT, out + (size_t)T_STEPS*DOUT*NB);
}